// Round 2
// baseline (35491.400 us; speedup 1.0000x reference)
//
#include <hip/hip_runtime.h>

#define Bv    32
#define Lv    256
#define Ev    256
#define HIDv  512
#define MEMv  128
#define HSv   64
#define NHv   4
#define OUTv  256
#define CTRLv 512
#define GATESv 2048
#define HPDv  129

#define NBLK  256
#define NTHR  512

// ws float offsets
#define G_OFF   1024                           // gates: 32*2048
#define H_OFF   (G_OFF + Bv*GATESv)            // hbuf: 2 * 32*512
#define C_OFF   (H_OFF + 2*Bv*HIDv)            // cbuf: 2 * 32*512
#define R_OFF   (C_OFF + 2*Bv*HIDv)            // rcbuf: 2 * 32*256
#define P_OFF   (R_OFF + 2*Bv*NHv*HSv)         // hp: 32*4*129

__device__ __forceinline__ float sigm(float x) { return 1.0f / (1.0f + __expf(-x)); }
__device__ __forceinline__ float tanh_(float x) {
  float ax = fabsf(x);
  float e = __expf(-2.0f * ax);
  float t = (1.0f - e) / (1.0f + e);
  return copysignf(t, x);
}
__device__ __forceinline__ float dot4(float4 a, float4 b) {
  return fmaf(a.x, b.x, fmaf(a.y, b.y, fmaf(a.z, b.z, a.w * b.w)));
}

// LLC-coherent (sc0 sc1) accesses: bypass non-coherent L1/L2, no fences needed.
__device__ __forceinline__ float gld(const float* p) {
  return __hip_atomic_load(p, __ATOMIC_RELAXED, __HIP_MEMORY_SCOPE_AGENT);
}
__device__ __forceinline__ void gst(float* p, float v) {
  __hip_atomic_store(p, v, __ATOMIC_RELAXED, __HIP_MEMORY_SCOPE_AGENT);
}

// Fence-free grid barrier: monotonic two-level counters (16 groups x 16 blocks),
// relaxed agent atomics (LLC). Data is exchanged via gld/gst (LLC-coherent), so
// the only ordering needed is vmcnt(0) before arrival. NO cache invalidation.
__device__ __forceinline__ void gbar(unsigned* bar, int bk) {
  asm volatile("s_waitcnt vmcnt(0) lgkmcnt(0)" ::: "memory");
  __syncthreads();
  if (threadIdx.x == 0) {
    unsigned g = __hip_atomic_load(&bar[0], __ATOMIC_RELAXED, __HIP_MEMORY_SCOPE_AGENT);
    unsigned* gc = &bar[64 + (bk >> 4) * 32];
    unsigned a = __hip_atomic_fetch_add(gc, 1u, __ATOMIC_RELAXED, __HIP_MEMORY_SCOPE_AGENT);
    if ((a & 15u) == 15u) {
      unsigned r = __hip_atomic_fetch_add(&bar[32], 1u, __ATOMIC_RELAXED, __HIP_MEMORY_SCOPE_AGENT);
      if ((r & 15u) == 15u)
        __hip_atomic_fetch_add(&bar[0], 1u, __ATOMIC_RELAXED, __HIP_MEMORY_SCOPE_AGENT);
    }
    while (__hip_atomic_load(&bar[0], __ATOMIC_RELAXED, __HIP_MEMORY_SCOPE_AGENT) == g)
      __builtin_amdgcn_s_sleep(2);
    asm volatile("" ::: "memory");
  }
  __syncthreads();
}

__device__ __forceinline__ void out_phase(int tt, int bb, int tid,
    const float* __restrict__ hsrc, const float* __restrict__ rcsrc,
    const float* __restrict__ W_out, const float* __restrict__ b_out,
    float* __restrict__ out, float (*oS)[772])
{
  const int j0 = bb * 37;
  if (j0 >= Bv * OUTv) return;
  const int b0 = j0 >> 8;
  const int jmax = (j0 + 36 < Bv*OUTv) ? (j0 + 36) : (Bv*OUTv - 1);
  const int nb = ((jmax >> 8) != b0) ? 2 : 1;
  // stage [h(512) | rc(256)] for the 1-2 batches this block covers
  for (int i = tid; i < nb * 768; i += NTHR) {
    int bs = i / 768, kk = i - bs * 768, bsel = b0 + bs;
    oS[bs][kk] = (kk < 512) ? gld(hsrc + bsel * HIDv + kk)
                            : gld(rcsrc + bsel * (NHv*HSv) + (kk - 512));
  }
  __syncthreads();
  const int q = tid & 15, oi = tid >> 4;
  for (int i = oi; i < 37; i += 32) {
    const int j = j0 + i;
    if (j >= Bv * OUTv) break;
    const int b = j >> 8, o = j & 255;
    const float4* w4 = (const float4*)(W_out + o * (HIDv + NHv*HSv));
    const float4* a4 = (const float4*)oS[b - b0];
    float a0=0.f, a1=0.f, a2=0.f, a3=0.f;
    #pragma unroll
    for (int i2 = 0; i2 < 12; i2 += 4) {
      a0 += dot4(a4[(i2+0)*16 + q], w4[(i2+0)*16 + q]);
      a1 += dot4(a4[(i2+1)*16 + q], w4[(i2+1)*16 + q]);
      a2 += dot4(a4[(i2+2)*16 + q], w4[(i2+2)*16 + q]);
      a3 += dot4(a4[(i2+3)*16 + q], w4[(i2+3)*16 + q]);
    }
    float acc = (a0+a1)+(a2+a3);
    acc += __shfl_xor(acc, 1);
    acc += __shfl_xor(acc, 2);
    acc += __shfl_xor(acc, 4);
    acc += __shfl_xor(acc, 8);
    if (q == 0) out[((size_t)b * Lv + tt) * OUTv + o] = acc + b_out[o];
  }
}

__global__ __launch_bounds__(NTHR) void ntm_kernel(
    const float* __restrict__ x, const float* __restrict__ W_ih, const float* __restrict__ W_hh,
    const float* __restrict__ b_ih, const float* __restrict__ b_hh,
    const float* __restrict__ W_head, const float* __restrict__ b_head,
    const float* __restrict__ W_out, const float* __restrict__ b_out,
    float* __restrict__ out, float* __restrict__ ws)
{
  const int bk = blockIdx.x, tid = threadIdx.x;
  unsigned* bar = (unsigned*)ws;
  float* gates = ws + G_OFF;
  float* hbuf  = ws + H_OFF;   // [parity][b][512]
  float* cbuf  = ws + C_OFF;   // [parity][b][512]
  float* rcbuf = ws + R_OFF;   // [parity][b][256]
  float* hp    = ws + P_OFF;   // [b][n][129]
  float* memv  = out + (size_t)Bv * Lv * OUTv;  // mem state lives in d_out
  float* hout  = memv + Bv * MEMv * HSv;
  float* cout_ = hout + Bv * HIDv;

  // LDS. actS: [b][ rc(0..255) | h(256..767) ], stride 772 (= 4 mod 32 -> <=4-way)
  __shared__ __align__(16) float actS[Bv][772];          // 98.8 KB
  __shared__ float pLDS[16][8][32];                      // 16 KB
  __shared__ __align__(16) float h_lds[HIDv];            // 2 KB
  __shared__ __align__(16) float rk[NHv][HSv];
  __shared__ __align__(16) float wk[NHv][HSv];
  __shared__ float pr[NHv][MEMv], pw[NHv][MEMv];
  __shared__ float strl[NHv];
  __shared__ __align__(16) float outS[2][772];           // 6.2 KB

  // --- init: zero state buffers (via LLC so later gld sees them) ---
  for (int i = bk * NTHR + tid; i < 2*Bv*HIDv + 2*Bv*HIDv + 2*Bv*NHv*HSv; i += NBLK*NTHR)
    gst(ws + H_OFF + i, 0.f);
  for (int i = bk * NTHR + tid; i < Bv*MEMv*HSv; i += NBLK*NTHR)
    memv[i] = 0.f;
  gbar(bar, bk);

  for (int t = 0; t < Lv; ++t) {
    // ===== phase 1: gates = [x_t, rc(t-1)] @ W_ih^T + h(t-1) @ W_hh^T + b =====
    {
      const float* hprev  = hbuf  + ((t + 1) & 1) * (Bv*HIDv);
      const float* rcprev = rcbuf + ((t + 1) & 1) * (Bv*NHv*HSv);
      for (int i = tid; i < Bv*256; i += NTHR) {
        int b = i >> 8, k = i & 255;
        actS[b][k] = gld(rcprev + b * 256 + k);
      }
      for (int i = tid; i < Bv*512; i += NTHR) {
        int b = i >> 9, k = i & 511;
        actS[b][256 + k] = gld(hprev + b * 512 + k);
      }
      __syncthreads();
      // thread = (half, q, b): 8 rows x 64-k chunk, act loaded once, reused 8x
      const int b = tid & 31, q = (tid >> 5) & 7, half = tid >> 8;
      const int kc = q * 64;
      const float* wbase = (half ? W_hh : W_ih) + (size_t)(bk * 8) * 512 + kc;
      float4 av[16];
      if (half == 0) {
        if (q < 4) {
          const float4* x4 = (const float4*)(x + ((size_t)b * Lv + t) * Ev + kc);
          #pragma unroll
          for (int i = 0; i < 16; ++i) av[i] = x4[i];
        } else {
          const float4* a4 = (const float4*)&actS[b][kc - 256];
          #pragma unroll
          for (int i = 0; i < 16; ++i) av[i] = a4[i];
        }
      } else {
        const float4* a4 = (const float4*)&actS[b][256 + kc];
        #pragma unroll
        for (int i = 0; i < 16; ++i) av[i] = a4[i];
      }
      const int qq = half * 8 + q;
      #pragma unroll
      for (int r = 0; r < 8; ++r) {
        const float4* w4 = (const float4*)(wbase + r * 512);
        float s0=0.f, s1=0.f, s2=0.f, s3=0.f;
        #pragma unroll
        for (int i = 0; i < 16; i += 4) {
          s0 += dot4(av[i+0], w4[i+0]); s1 += dot4(av[i+1], w4[i+1]);
          s2 += dot4(av[i+2], w4[i+2]); s3 += dot4(av[i+3], w4[i+3]);
        }
        pLDS[qq][r][b] = (s0+s1)+(s2+s3);
      }
      __syncthreads();
      if (tid < 256) {
        const int r = tid >> 5, b2 = tid & 31, row = bk * 8 + r;
        float s = 0.f;
        #pragma unroll
        for (int j = 0; j < 16; ++j) s += pLDS[j][r][b2];
        gst(&gates[b2 * GATESv + row], s + b_ih[row] + b_hh[row]);
      }
    }
    gbar(bar, bk);

    // ===== phase 2: LSTM pointwise (redundant per sub) + head GEMM (used rows) =====
    {
      const int b = bk >> 3, sub = bk & 7;
      const float* gb = gates + b * GATESv;
      const int k = tid;
      float ig = sigm(gld(gb + k));
      float fg = sigm(gld(gb + 512 + k));
      float gg = tanh_(gld(gb + 1024 + k));
      float og = sigm(gld(gb + 1536 + k));
      float cold = gld(cbuf + (t & 1) * (Bv*HIDv) + b * HIDv + k);
      float cnew = fmaf(fg, cold, ig * gg);
      float hnew = og * tanh_(cnew);
      h_lds[k] = hnew;
      if (sub == 0) {
        gst(cbuf + ((t + 1) & 1) * (Bv*HIDv) + b * HIDv + k, cnew);
        gst(hbuf + (t & 1) * (Bv*HIDv) + b * HIDv + k, hnew);
      }
      __syncthreads();
      const int q = tid & 7;
      const int li1 = (sub == 7) ? 516 : (sub * 65 + 65);
      for (int li = sub * 65 + (tid >> 3); li < li1; li += 64) {
        const int n = li / 129, d = li - n * 129;
        const int row = n * 195 + d;
        const float4* w4 = (const float4*)(W_head + (size_t)row * HIDv);
        const float4* h4 = (const float4*)h_lds;
        float a0=0.f, a1=0.f, a2=0.f, a3=0.f;
        #pragma unroll
        for (int i = 0; i < 16; i += 4) {
          a0 += dot4(h4[(i+0)*8 + q], w4[(i+0)*8 + q]);
          a1 += dot4(h4[(i+1)*8 + q], w4[(i+1)*8 + q]);
          a2 += dot4(h4[(i+2)*8 + q], w4[(i+2)*8 + q]);
          a3 += dot4(h4[(i+3)*8 + q], w4[(i+3)*8 + q]);
        }
        float acc = (a0+a1)+(a2+a3);
        acc += __shfl_xor(acc, 1);
        acc += __shfl_xor(acc, 2);
        acc += __shfl_xor(acc, 4);
        if (q == 0) {
          acc += b_head[row];
          if (d == 128) acc = sigm(acc);   // write strength pre-sigmoided
          gst(&hp[(b * NHv + n) * HPDv + d], acc);
        }
      }
    }
    gbar(bar, bk);

    // ===== phase 3: attention (blocks 0..31) || out(t-1) (blocks 32..255) =====
    if (bk < Bv) {
      const int b = bk;
      for (int i = tid; i < NHv * HSv; i += NTHR) {
        const int n = i >> 6, d = i & 63;
        rk[n][d] = gld(&hp[(b*NHv + n) * HPDv + d]);
        wk[n][d] = gld(&hp[(b*NHv + n) * HPDv + HSv + d]);
      }
      if (tid < NHv) strl[tid] = gld(&hp[(b*NHv + tid) * HPDv + 2*HSv]);
      __syncthreads();
      {
        const int n = tid >> 7, m = tid & 127;
        const float4* mr  = (const float4*)(memv + ((size_t)b * MEMv + m) * HSv);
        const float4* rk4 = (const float4*)rk[n];
        const float4* wk4 = (const float4*)wk[n];
        float sr0=0.f, sr1=0.f, sw0=0.f, sw1=0.f;
        #pragma unroll
        for (int i = 0; i < 16; i += 2) {
          float4 m0 = mr[i], m1 = mr[i+1];
          sr0 += dot4(m0, rk4[i]);   sw0 += dot4(m0, wk4[i]);
          sr1 += dot4(m1, rk4[i+1]); sw1 += dot4(m1, wk4[i+1]);
        }
        pr[n][m] = (sr0 + sr1) * 0.125f;
        pw[n][m] = (sw0 + sw1) * 0.125f;
      }
      __syncthreads();
      {
        const int w = tid >> 6, lane = tid & 63;
        float* rowp = (w < NHv) ? pr[w] : pw[w - NHv];
        float va = rowp[lane], vb = rowp[lane + 64];
        float mx = fmaxf(va, vb);
        for (int off = 32; off > 0; off >>= 1) mx = fmaxf(mx, __shfl_xor(mx, off));
        float ea = __expf(va - mx), eb = __expf(vb - mx);
        float s = ea + eb;
        for (int off = 32; off > 0; off >>= 1) s += __shfl_xor(s, off);
        float inv = 1.0f / s;
        rowp[lane] = ea * inv; rowp[lane + 64] = eb * inv;
      }
      __syncthreads();
      if (tid < NHv * HSv) {
        const int n = tid >> 6, hh = tid & 63;
        const float* mcol = memv + (size_t)b * MEMv * HSv + hh;
        float a0=0.f, a1=0.f, a2=0.f, a3=0.f;
        for (int m = 0; m < MEMv; m += 4) {
          a0 += pr[n][m+0] * mcol[(m+0) * HSv];
          a1 += pr[n][m+1] * mcol[(m+1) * HSv];
          a2 += pr[n][m+2] * mcol[(m+2) * HSv];
          a3 += pr[n][m+3] * mcol[(m+3) * HSv];
        }
        gst(&rcbuf[(t & 1) * (Bv*NHv*HSv) + (b * NHv + n) * HSv + hh], (a0+a1)+(a2+a3));
      }
      __syncthreads();
      {
        const int hh = tid & 63, mg = tid >> 6;
        const float s0 = strl[0]*wk[0][hh], s1 = strl[1]*wk[1][hh],
                    s2 = strl[2]*wk[2][hh], s3 = strl[3]*wk[3][hh];
        for (int m = mg; m < MEMv; m += 8) {
          float add = pw[0][m]*s0 + pw[1][m]*s1 + pw[2][m]*s2 + pw[3][m]*s3;
          memv[((size_t)b * MEMv + m) * HSv + hh] += add;
        }
      }
    } else if (t > 0) {
      out_phase(t - 1, bk - 32, tid,
                hbuf  + ((t + 1) & 1) * (Bv*HIDv),
                rcbuf + ((t + 1) & 1) * (Bv*NHv*HSv),
                W_out, b_out, out, outS);
    }
    gbar(bar, bk);
  }

  // ===== final: out(L-1) + copy h, c states to d_out =====
  if (bk >= 32) {
    out_phase(Lv - 1, bk - 32, tid,
              hbuf + (Bv*HIDv),          // h(255): parity 1
              rcbuf + (Bv*NHv*HSv),      // rc(255): parity 1
              W_out, b_out, out, outS);
  } else {
    const int idx = bk * NTHR + tid;     // 0..16383
    hout[idx]  = gld(hbuf + Bv*HIDv + idx);   // h(255), parity 1
    cout_[idx] = gld(cbuf + idx);             // c(255), parity 0
  }
}

extern "C" void kernel_launch(void* const* d_in, const int* in_sizes, int n_in,
                              void* d_out, int out_size, void* d_ws, size_t ws_size,
                              hipStream_t stream) {
  const float* x      = (const float*)d_in[0];
  const float* W_ih   = (const float*)d_in[1];
  const float* W_hh   = (const float*)d_in[2];
  const float* b_ih   = (const float*)d_in[3];
  const float* b_hh   = (const float*)d_in[4];
  const float* W_head = (const float*)d_in[5];
  const float* b_head = (const float*)d_in[6];
  const float* W_out  = (const float*)d_in[7];
  const float* b_out  = (const float*)d_in[8];
  float* out = (float*)d_out;
  float* ws  = (float*)d_ws;

  // reset barrier state (monotonic counters must start consistent; ws is
  // poisoned to 0xAA once by the harness)
  (void)hipMemsetAsync(d_ws, 0, 4096, stream);

  void* args[] = { (void*)&x, (void*)&W_ih, (void*)&W_hh, (void*)&b_ih, (void*)&b_hh,
                   (void*)&W_head, (void*)&b_head, (void*)&W_out, (void*)&b_out,
                   (void*)&out, (void*)&ws };
  (void)hipLaunchCooperativeKernel((const void*)ntm_kernel, dim3(NBLK), dim3(NTHR),
                                   args, 0, stream);
}

// Round 3
// 29755.826 us; speedup vs baseline: 1.1928x; 1.1928x over previous
//
#include <hip/hip_runtime.h>

#define Bv 32
#define Lv 256
#define Ev 256
#define HIDv 512
#define MEMv 128
#define HSv 64
#define NHv 4
#define OUTv 256

#define NBLK 256
#define NTHR 512

// ws float offsets
#define H_OFF 1024                      // hbuf: 2 * 32*512
#define R_OFF (H_OFF + 2*Bv*HIDv)       // rcbuf: 2 * 32*256

__device__ __forceinline__ float sigm(float x){ return 1.f/(1.f+__expf(-x)); }
__device__ __forceinline__ float tanh_(float x){
  float ax = fabsf(x); float e = __expf(-2.f*ax);
  float t = (1.f-e)/(1.f+e); return copysignf(t, x);
}
__device__ __forceinline__ float dot4(float4 a, float4 b){
  return fmaf(a.x,b.x,fmaf(a.y,b.y,fmaf(a.z,b.z,a.w*b.w)));
}

// LLC-coherent scalar ops (sc0 sc1): bypass non-coherent L1/L2, no fences needed.
__device__ __forceinline__ float gld(const float* p){
  return __hip_atomic_load(p,__ATOMIC_RELAXED,__HIP_MEMORY_SCOPE_AGENT);
}
__device__ __forceinline__ void gst(float* p, float v){
  __hip_atomic_store(p,v,__ATOMIC_RELAXED,__HIP_MEMORY_SCOPE_AGENT);
}
// 16B LLC-coherent loads (coalesced fabric transactions)
__device__ __forceinline__ float4 gld4(const float4* p){
  float4 r;
  asm volatile("global_load_dwordx4 %0, %1, off sc0 sc1\n\ts_waitcnt vmcnt(0)"
    : "=&v"(r) : "v"(p) : "memory");
  return r;
}
__device__ __forceinline__ void gld4_2(float4& r0, float4& r1,
                                       const float4* p0, const float4* p1){
  asm volatile("global_load_dwordx4 %0, %2, off sc0 sc1\n\t"
               "global_load_dwordx4 %1, %3, off sc0 sc1\n\t"
               "s_waitcnt vmcnt(0)"
    : "=&v"(r0), "=&v"(r1) : "v"(p0), "v"(p1) : "memory");
}

// Fence-free grid barrier: monotonic two-level counters, relaxed agent atomics.
__device__ __forceinline__ void gbar(unsigned* bar, int bk){
  asm volatile("s_waitcnt vmcnt(0) lgkmcnt(0)" ::: "memory");
  __syncthreads();
  if (threadIdx.x == 0){
    unsigned g = __hip_atomic_load(&bar[0],__ATOMIC_RELAXED,__HIP_MEMORY_SCOPE_AGENT);
    unsigned* gc = &bar[64 + (bk>>4)*32];
    unsigned a = __hip_atomic_fetch_add(gc,1u,__ATOMIC_RELAXED,__HIP_MEMORY_SCOPE_AGENT);
    if ((a & 15u) == 15u){
      unsigned r = __hip_atomic_fetch_add(&bar[32],1u,__ATOMIC_RELAXED,__HIP_MEMORY_SCOPE_AGENT);
      if ((r & 15u) == 15u)
        __hip_atomic_fetch_add(&bar[0],1u,__ATOMIC_RELAXED,__HIP_MEMORY_SCOPE_AGENT);
    }
    while (__hip_atomic_load(&bar[0],__ATOMIC_RELAXED,__HIP_MEMORY_SCOPE_AGENT) == g)
      __builtin_amdgcn_s_sleep(2);
    asm volatile("" ::: "memory");
  }
  __syncthreads();
}

__device__ __forceinline__ void out_phase(int tt, int j0, int tid,
    const float4* __restrict__ h4src, const float4* __restrict__ rc4src,
    const float* __restrict__ W_out, const float* __restrict__ b_out,
    float* __restrict__ out, float (*oS)[768])
{
  if (j0 >= Bv*OUTv) return;                     // blocks past the tail idle
  const int b0 = j0 >> 8;
  const int jmax = (j0+36 < Bv*OUTv) ? j0+36 : Bv*OUTv-1;
  const int nb = ((jmax>>8) != b0) ? 2 : 1;
  float4* oS4 = (float4*)oS;                     // [2][192] f4: [h 128 | rc 64]
  for (int idx = tid; idx < nb*192; idx += NTHR){
    int bs = idx/192, kk = idx - bs*192, bsel = b0 + bs;
    const float4* src = (kk < 128) ? (h4src + bsel*128 + kk)
                                   : (rc4src + bsel*64 + (kk-128));
    oS4[bs*192 + kk] = gld4(src);
  }
  __syncthreads();
  const int q = tid & 15, oi = tid >> 4;
  for (int i = oi; i < 37; i += 32){
    const int j = j0 + i;
    if (j >= Bv*OUTv) break;
    const int b = j >> 8, o = j & 255;
    const float4* w4 = (const float4*)(W_out + (size_t)o*(HIDv + NHv*HSv));
    const float4* a4 = oS4 + (b - b0)*192;
    float a0=0.f,a1=0.f,a2=0.f,a3=0.f;
    #pragma unroll
    for (int i2 = 0; i2 < 12; i2 += 4){
      a0 += dot4(a4[(i2+0)*16+q], w4[(i2+0)*16+q]);
      a1 += dot4(a4[(i2+1)*16+q], w4[(i2+1)*16+q]);
      a2 += dot4(a4[(i2+2)*16+q], w4[(i2+2)*16+q]);
      a3 += dot4(a4[(i2+3)*16+q], w4[(i2+3)*16+q]);
    }
    float acc = (a0+a1)+(a2+a3);
    acc += __shfl_xor(acc,1); acc += __shfl_xor(acc,2);
    acc += __shfl_xor(acc,4); acc += __shfl_xor(acc,8);
    if (q == 0) out[((size_t)b*Lv + tt)*OUTv + o] = acc + b_out[o];
  }
}

__global__ __launch_bounds__(NTHR, 2) void ntm_kernel(
    const float* __restrict__ x, const float* __restrict__ W_ih, const float* __restrict__ W_hh,
    const float* __restrict__ b_ih, const float* __restrict__ b_hh,
    const float* __restrict__ W_head, const float* __restrict__ b_head,
    const float* __restrict__ W_out, const float* __restrict__ b_out,
    float* __restrict__ out, float* __restrict__ ws)
{
  const int bk = blockIdx.x, tid = threadIdx.x;
  unsigned* bar = (unsigned*)ws;
  float* hbuf  = ws + H_OFF;                     // [parity][b][512]
  float* rcbuf = ws + R_OFF;                     // [parity][b][256]
  float* memv  = out + (size_t)Bv*Lv*OUTv;
  float* hout  = memv + Bv*MEMv*HSv;
  float* cout_ = hout + Bv*HIDv;

  // bk = bg*32 + rg  =>  XCD (bk%8) = rg%8: weight slices stay XCD-L2-resident
  const int rg = bk & 31, bg = bk >> 5, b0 = bg*4;

  __shared__ __align__(16) float actS[4][1024];  // [bb][ x(256) | rc(256) | h(512) ]
  __shared__ float gS[64][4];                    // gate partials [q*16+j][bb]
  __shared__ float cS[16][4];                    // c state, LDS-resident all steps
  __shared__ float biasS[64];
  __shared__ __align__(16) float memS[128][68];  // mem state (attn blocks), stride 68
  __shared__ __align__(16) float hS[512];
  __shared__ __align__(16) float rkS[4][64], wkS[4][64];
  __shared__ float pr[4][128], pw[4][128];
  __shared__ float strS[4];
  __shared__ __align__(16) float outS[2][768];

  // ---- init ----
  if (tid < 64){
    int gr = (tid>>4)*512 + rg*16 + (tid&15);
    biasS[tid] = b_ih[gr] + b_hh[gr];
    cS[tid&15][tid>>4] = 0.f;
  }
  if (bk < Bv) for (int i = tid; i < 128*68; i += NTHR) ((float*)memS)[i] = 0.f;
  for (int i = bk*NTHR + tid; i < 2*Bv*HIDv + 2*Bv*NHv*HSv; i += NBLK*NTHR)
    gst(ws + H_OFF + i, 0.f);
  gbar(bar, bk);

  for (int t = 0; t < Lv; ++t){
    // ===== P1: gates (64 rows x 4 batches) + block-local LSTM -> h(t) =====
    {
      const float4* hprev4  = (const float4*)(hbuf  + ((t+1)&1)*Bv*HIDv);
      const float4* rcprev4 = (const float4*)(rcbuf + ((t+1)&1)*Bv*NHv*HSv);
      float4* aS4 = (float4*)actS;               // [4][256] f4
      if (tid < 256){
        int bbr = tid>>6, kqr = tid&63;          // rc f4
        int jh = 256 + tid; int bbh = jh>>7, kqh = jh&127;  // h upper f4
        float4 r0, r1;
        gld4_2(r0, r1, rcprev4 + (b0+bbr)*64 + kqr, hprev4 + (b0+bbh)*128 + kqh);
        aS4[bbr*256 + 64 + kqr]  = r0;
        aS4[bbh*256 + 128 + kqh] = r1;
      } else {
        int jh = tid - 256; int bbh = jh>>7, kqh = jh&127;  // h lower f4
        float4 r = gld4(hprev4 + (b0+bbh)*128 + kqh);
        aS4[bbh*256 + 128 + kqh] = r;
        int tx = tid - 256; int bbx = tx>>6, kqx = tx&63;   // x f4 (read-only: normal ld)
        aS4[bbx*256 + kqx] = ((const float4*)x)[((size_t)(b0+bbx)*Lv + t)*64 + kqx];
      }
      __syncthreads();

      const int kc = tid & 15, rgrp = (tid>>4)&7, bb = tid>>7;
      float4 av[16];
      #pragma unroll
      for (int i = 0; i < 16; ++i) av[i] = ((const float4*)actS)[bb*256 + kc + 16*i];
      float accs[8];
      #pragma unroll
      for (int r8 = 0; r8 < 8; ++r8){
        const int lr = rgrp*8 + r8;
        const int gr = (lr>>4)*512 + rg*16 + (lr&15);
        const float4* wi4 = (const float4*)(W_ih + (size_t)gr*512);
        const float4* wh4 = (const float4*)(W_hh + (size_t)gr*512);
        float s0=0.f,s1=0.f,s2=0.f,s3=0.f;
        #pragma unroll
        for (int i = 0; i < 8; i += 4){
          s0 += dot4(av[i+0], wi4[kc+16*(i+0)]); s1 += dot4(av[i+1], wi4[kc+16*(i+1)]);
          s2 += dot4(av[i+2], wi4[kc+16*(i+2)]); s3 += dot4(av[i+3], wi4[kc+16*(i+3)]);
        }
        #pragma unroll
        for (int i = 8; i < 16; i += 4){
          s0 += dot4(av[i+0], wh4[kc+16*(i-8)]); s1 += dot4(av[i+1], wh4[kc+16*(i-7)]);
          s2 += dot4(av[i+2], wh4[kc+16*(i-6)]); s3 += dot4(av[i+3], wh4[kc+16*(i-5)]);
        }
        accs[r8] = (s0+s1)+(s2+s3);
      }
      #pragma unroll
      for (int r8 = 0; r8 < 8; ++r8){
        float v = accs[r8];
        v += __shfl_xor(v,1); v += __shfl_xor(v,2);
        v += __shfl_xor(v,4); v += __shfl_xor(v,8);
        if (kc == 0) gS[rgrp*8+r8][bb] = v;
      }
      __syncthreads();
      if (tid < 64){
        const int j = tid & 15, bb2 = tid >> 4;
        float ig = sigm (gS[   j][bb2] + biasS[   j]);
        float fg = sigm (gS[16+j][bb2] + biasS[16+j]);
        float gg = tanh_(gS[32+j][bb2] + biasS[32+j]);
        float og = sigm (gS[48+j][bb2] + biasS[48+j]);
        float cn = fmaf(fg, cS[j][bb2], ig*gg);
        cS[j][bb2] = cn;
        float hn = og * tanh_(cn);
        gst(hbuf + (t&1)*Bv*HIDv + (size_t)(b0+bb2)*HIDv + rg*16 + j, hn);
      }
    }
    gbar(bar, bk);

    // ===== P2: [blocks 0..31] head GEMM + attention + rc || [32..255] out(t-1) =====
    if (bk < Bv){
      const int b = bk;
      const float4* hcur4 = (const float4*)(hbuf + (t&1)*Bv*HIDv) + b*128;
      if (tid < 128) ((float4*)hS)[tid] = gld4(hcur4 + tid);
      __syncthreads();
      {
        const int q = tid & 7, ro = tid >> 3;
        for (int li = ro; li < 516; li += 64){
          int n = li/129, d = li - n*129;
          int row = n*195 + d;
          const float4* w4 = (const float4*)(W_head + (size_t)row*HIDv);
          const float4* h4 = (const float4*)hS;
          float a0=0.f,a1=0.f,a2=0.f,a3=0.f;
          #pragma unroll
          for (int i = 0; i < 16; i += 4){
            a0 += dot4(h4[(i+0)*8+q], w4[(i+0)*8+q]);
            a1 += dot4(h4[(i+1)*8+q], w4[(i+1)*8+q]);
            a2 += dot4(h4[(i+2)*8+q], w4[(i+2)*8+q]);
            a3 += dot4(h4[(i+3)*8+q], w4[(i+3)*8+q]);
          }
          float acc = (a0+a1)+(a2+a3);
          acc += __shfl_xor(acc,1); acc += __shfl_xor(acc,2); acc += __shfl_xor(acc,4);
          if (q == 0){
            acc += b_head[row];
            if (d < 64)        rkS[n][d]     = acc;
            else if (d < 128)  wkS[n][d-64]  = acc;
            else               strS[n]       = sigm(acc);
          }
        }
      }
      __syncthreads();
      { // QK^T (read & write keys), scale 1/8
        const int n = tid >> 7, m = tid & 127;
        const float4* m4  = (const float4*)&memS[m][0];
        const float4* rk4 = (const float4*)rkS[n];
        const float4* wk4 = (const float4*)wkS[n];
        float sr0=0.f,sr1=0.f,sw0=0.f,sw1=0.f;
        #pragma unroll
        for (int i = 0; i < 16; i += 2){
          float4 v0 = m4[i], v1 = m4[i+1];
          sr0 += dot4(v0, rk4[i]);   sw0 += dot4(v0, wk4[i]);
          sr1 += dot4(v1, rk4[i+1]); sw1 += dot4(v1, wk4[i+1]);
        }
        pr[n][m] = (sr0+sr1)*0.125f;
        pw[n][m] = (sw0+sw1)*0.125f;
      }
      __syncthreads();
      { // softmax over m: 8 waves, one (tensor,head) row each
        const int w = tid >> 6, lane = tid & 63;
        float* rowp = (w < NHv) ? pr[w] : pw[w-NHv];
        float va = rowp[lane], vb = rowp[lane+64];
        float mx = fmaxf(va, vb);
        for (int off = 32; off > 0; off >>= 1) mx = fmaxf(mx, __shfl_xor(mx, off));
        float ea = __expf(va-mx), eb = __expf(vb-mx);
        float s = ea + eb;
        for (int off = 32; off > 0; off >>= 1) s += __shfl_xor(s, off);
        float inv = 1.f/s;
        rowp[lane] = ea*inv; rowp[lane+64] = eb*inv;
      }
      __syncthreads();
      if (tid < 256){ // rc = pr @ mem (pre-update mem)
        const int n = tid >> 6, hh = tid & 63;
        float a0=0.f,a1=0.f,a2=0.f,a3=0.f;
        for (int m = 0; m < 128; m += 4){
          a0 += pr[n][m+0]*memS[m+0][hh];
          a1 += pr[n][m+1]*memS[m+1][hh];
          a2 += pr[n][m+2]*memS[m+2][hh];
          a3 += pr[n][m+3]*memS[m+3][hh];
        }
        gst(&rcbuf[(t&1)*Bv*NHv*HSv + (b*NHv+n)*HSv + hh], (a0+a1)+(a2+a3));
      }
      __syncthreads();
      { // mem += ww^T (str*wk)
        const int hh = tid & 63, mg = tid >> 6;
        const float s0 = strS[0]*wkS[0][hh], s1 = strS[1]*wkS[1][hh],
                    s2 = strS[2]*wkS[2][hh], s3 = strS[3]*wkS[3][hh];
        for (int m = mg; m < 128; m += 8){
          float add = pw[0][m]*s0 + pw[1][m]*s1 + pw[2][m]*s2 + pw[3][m]*s3;
          memS[m][hh] += add;
        }
      }
    } else if (t > 0){
      out_phase(t-1, (bk-32)*37, tid,
                (const float4*)(hbuf  + ((t+1)&1)*Bv*HIDv),
                (const float4*)(rcbuf + ((t+1)&1)*Bv*NHv*HSv),
                W_out, b_out, out, outS);
    }
    gbar(bar, bk);
  }

  // ===== final: out(255); dump mem/h (attn blocks) and c (all blocks) =====
  if (bk >= 32){
    out_phase(Lv-1, (bk-32)*37, tid,
              (const float4*)(hbuf  + Bv*HIDv),      // parity 1 = h(255)
              (const float4*)(rcbuf + Bv*NHv*HSv),   // parity 1 = rc(255)
              W_out, b_out, out, outS);
  } else {
    const int b = bk;
    if (tid < 128)
      ((float4*)(hout + (size_t)b*HIDv))[tid] =
        gld4((const float4*)(hbuf + Bv*HIDv) + b*128 + tid);
    for (int i = tid; i < MEMv*HSv; i += NTHR){
      int m = i >> 6, hh = i & 63;
      memv[((size_t)b*MEMv + m)*HSv + hh] = memS[m][hh];
    }
  }
  if (tid < 64){
    int j = tid & 15, bb = tid >> 4;
    cout_[(size_t)(b0+bb)*HIDv + rg*16 + j] = cS[j][bb];
  }
}

extern "C" void kernel_launch(void* const* d_in, const int* in_sizes, int n_in,
                              void* d_out, int out_size, void* d_ws, size_t ws_size,
                              hipStream_t stream){
  const float* x      = (const float*)d_in[0];
  const float* W_ih   = (const float*)d_in[1];
  const float* W_hh   = (const float*)d_in[2];
  const float* b_ih   = (const float*)d_in[3];
  const float* b_hh   = (const float*)d_in[4];
  const float* W_head = (const float*)d_in[5];
  const float* b_head = (const float*)d_in[6];
  const float* W_out  = (const float*)d_in[7];
  const float* b_out  = (const float*)d_in[8];
  float* out = (float*)d_out;
  float* ws  = (float*)d_ws;

  (void)hipMemsetAsync(d_ws, 0, 4096, stream);   // barrier counters

  void* args[] = { (void*)&x, (void*)&W_ih, (void*)&W_hh, (void*)&b_ih, (void*)&b_hh,
                   (void*)&W_head, (void*)&b_head, (void*)&W_out, (void*)&b_out,
                   (void*)&out, (void*)&ws };
  (void)hipLaunchCooperativeKernel((const void*)ntm_kernel, dim3(NBLK), dim3(NTHR),
                                   args, 0, stream);
}

// Round 4
// 13309.283 us; speedup vs baseline: 2.6667x; 2.2357x over previous
//
#include <hip/hip_runtime.h>

#define Bv 32
#define Lv 256
#define HIDv 512
#define MEMv 128
#define HSv 64
#define NHv 4
#define OUTv 256
#define NBLK 256
#define NTHR 512

// ws float offsets
#define H_OFF 1024                       // hbuf: 2 * 32*512
#define R_OFF (H_OFF + 2*Bv*HIDv)        // rcbuf: 2 * 32*256
#define P_OFF (R_OFF + 2*Bv*NHv*HSv)     // hp: 32 x 520

// hwreg(HW_REG_XCC_ID=20, offset 0, size 32)
#define XCC_GETREG_IMM ((31 << 11) | 20)

__device__ __forceinline__ float sigm(float x){ return 1.f/(1.f+__expf(-x)); }
__device__ __forceinline__ float tanh_(float x){
  float ax = fabsf(x); float e = __expf(-2.f*ax);
  float t = (1.f-e)/(1.f+e); return copysignf(t, x);
}
__device__ __forceinline__ float dot4(float4 a, float4 b){
  return fmaf(a.x,b.x,fmaf(a.y,b.y,fmaf(a.z,b.z,a.w*b.w)));
}

// LLC-coherent (sc0 sc1) ops: bypass non-coherent L1/L2 -> no fences needed.
__device__ __forceinline__ float gld(const float* p){
  return __hip_atomic_load(p,__ATOMIC_RELAXED,__HIP_MEMORY_SCOPE_AGENT);
}
__device__ __forceinline__ void gst(float* p, float v){
  __hip_atomic_store(p,v,__ATOMIC_RELAXED,__HIP_MEMORY_SCOPE_AGENT);
}
__device__ __forceinline__ float4 gld4(const float4* p){
  float4 r;
  asm volatile("global_load_dwordx4 %0, %1, off sc0 sc1\n\ts_waitcnt vmcnt(0)"
    : "=&v"(r) : "v"(p) : "memory");
  return r;
}
__device__ __forceinline__ void gld4_2(float4& r0, float4& r1,
                                       const float4* p0, const float4* p1){
  asm volatile("global_load_dwordx4 %0, %2, off sc0 sc1\n\t"
               "global_load_dwordx4 %1, %3, off sc0 sc1\n\t"
               "s_waitcnt vmcnt(0)"
    : "=&v"(r0), "=&v"(r1) : "v"(p0), "v"(p1) : "memory");
}

// Group barrier: 32 blocks of batch-group g. Monotonic counters, LLC atomics.
// Safe: release only fires after all 32 of this generation arrive, and no member
// can start the next generation before passing this one.
__device__ __forceinline__ void gbarg(unsigned* bar, int g){
  asm volatile("s_waitcnt vmcnt(0) lgkmcnt(0)" ::: "memory");
  __syncthreads();
  if (threadIdx.x == 0){
    unsigned* arr = &bar[512 + g*64];
    unsigned* rel = arr + 32;
    unsigned gen = __hip_atomic_load(rel,__ATOMIC_RELAXED,__HIP_MEMORY_SCOPE_AGENT);
    unsigned a = __hip_atomic_fetch_add(arr,1u,__ATOMIC_RELAXED,__HIP_MEMORY_SCOPE_AGENT);
    if ((a & 31u) == 31u)
      __hip_atomic_fetch_add(rel,1u,__ATOMIC_RELAXED,__HIP_MEMORY_SCOPE_AGENT);
    while (__hip_atomic_load(rel,__ATOMIC_RELAXED,__HIP_MEMORY_SCOPE_AGENT) == gen)
      __builtin_amdgcn_s_sleep(2);
    asm volatile("" ::: "memory");
  }
  __syncthreads();
}

// out GEMM for 37 group-local outputs starting at orank*37 (group outputs 0..1023)
__device__ __forceinline__ void out_phase(int tt, int b0, int orank, int tid,
    const float4* __restrict__ h4, const float4* __restrict__ rc4,
    const float* __restrict__ W_out, const float* __restrict__ b_out,
    float* __restrict__ out, float (*oS)[772])
{
  const int j0 = orank*37;
  if (j0 >= 4*OUTv) return;
  const int jend = (j0+37 < 4*OUTv) ? j0+37 : 4*OUTv;
  const int lb0 = j0 >> 8, lb1 = (jend-1) >> 8;
  const int nb = lb1 - lb0 + 1;                    // 1 or 2
  for (int idx = tid; idx < nb*192; idx += NTHR){
    int bs = idx/192, kk = idx - bs*192;
    int b = b0 + lb0 + bs;
    float4 v = (kk < 128) ? gld4(h4 + b*128 + kk) : gld4(rc4 + b*64 + (kk-128));
    ((float4*)oS[bs])[kk] = v;
  }
  __syncthreads();
  const int q = tid & 15, oi = tid >> 4;
  for (int i = oi; i < 37; i += 32){
    int jl = j0 + i;
    if (jl >= 4*OUTv) break;
    int lb = jl >> 8, o = jl & 255;
    const float4* w4 = (const float4*)(W_out + (size_t)o*768);
    const float4* a4 = (const float4*)oS[lb - lb0];
    float a0=0.f,a1=0.f,a2=0.f,a3=0.f;
    #pragma unroll
    for (int i2 = 0; i2 < 12; i2 += 4){
      a0 += dot4(a4[(i2+0)*16+q], w4[(i2+0)*16+q]);
      a1 += dot4(a4[(i2+1)*16+q], w4[(i2+1)*16+q]);
      a2 += dot4(a4[(i2+2)*16+q], w4[(i2+2)*16+q]);
      a3 += dot4(a4[(i2+3)*16+q], w4[(i2+3)*16+q]);
    }
    float acc = (a0+a1)+(a2+a3);
    acc += __shfl_xor(acc,1); acc += __shfl_xor(acc,2);
    acc += __shfl_xor(acc,4); acc += __shfl_xor(acc,8);
    if (q == 0) out[((size_t)(b0+lb)*Lv + tt)*OUTv + o] = acc + b_out[o];
  }
}

__global__ __launch_bounds__(NTHR) void ntm_kernel(
    const float* __restrict__ x, const float* __restrict__ W_ih, const float* __restrict__ W_hh,
    const float* __restrict__ b_ih, const float* __restrict__ b_hh,
    const float* __restrict__ W_head, const float* __restrict__ b_head,
    const float* __restrict__ W_out, const float* __restrict__ b_out,
    float* __restrict__ out, float* __restrict__ ws)
{
  const int tid = threadIdx.x;
  unsigned* bar = (unsigned*)ws;
  float* hbuf  = ws + H_OFF;                   // [parity][b][512]
  float* rcbuf = ws + R_OFF;                   // [parity][b][256]
  float* hp    = ws + P_OFF;                   // [b][520]
  float* memv  = out + (size_t)Bv*Lv*OUTv;
  float* hout  = memv + Bv*MEMv*HSv;
  float* cout_ = hout + Bv*HIDv;

  __shared__ __align__(16) float actS[4][1024];   // 16 KB: [bb][x|rc|h] or h(t) in P2a
  __shared__ float gS[64][4];
  __shared__ float cS[16][4];
  __shared__ float biasS[64];
  __shared__ __align__(16) float memS[128][68];   // 34.8 KB, attn blocks only
  __shared__ __align__(16) float rkS[4][64], wkS[4][64];
  __shared__ float pr[4][128], pw[4][128];
  __shared__ float strS[4];
  __shared__ __align__(16) float outS[2][772];
  __shared__ int sAsg[2];

  // ---- XCD-aware ticket assignment (dispatch-agnostic, spill-safe) ----
  if (tid == 0){
    unsigned xcd = ((unsigned)__builtin_amdgcn_s_getreg(XCC_GETREG_IMM)) & 7u;
    int bucket = 0, slot = 0;
    for (int p = 0; p < 8; ++p){
      unsigned pb = (xcd + (unsigned)p) & 7u;
      unsigned tk = __hip_atomic_fetch_add(&bar[128 + pb*32], 1u,
                      __ATOMIC_RELAXED, __HIP_MEMORY_SCOPE_AGENT);
      if (tk < 32u){ bucket = (int)pb; slot = (int)tk; break; }
    }
    sAsg[0] = bucket; sAsg[1] = slot;
  }
  __syncthreads();
  const int xcd = sAsg[0], slot = sAsg[1];
  const int rho = slot & 3;
  const int rg  = xcd*4 + rho;        // gate-weight slice 0..31 (4 per XCD)
  const int bg  = slot >> 2;          // batch group 0..7
  const int b0  = bg*4;
  const bool isA = (rho == 0) && ((xcd >> 2) == (bg & 1));
  const int abatch = b0 + (xcd & 3);
  const int orank  = (rho > 0) ? (xcd*3 + rho - 1) : (24 + (xcd & 3));

  // ---- init: bias, c, my h/rc parity-1 slices, mem ----
  if (tid < 64){
    int lr = tid;
    int gr = (lr>>4)*512 + rg*16 + (lr&15);
    biasS[lr] = b_ih[gr] + b_hh[gr];
    cS[tid&15][tid>>4] = 0.f;
    int j = tid & 15, bb = tid >> 4;
    gst(hbuf + Bv*HIDv + (size_t)(b0+bb)*HIDv + rg*16 + j, 0.f);
  }
  if (tid < 32){
    int j = tid & 7, bb = tid >> 3;
    gst(rcbuf + Bv*NHv*HSv + (size_t)(b0+bb)*(NHv*HSv) + rg*8 + j, 0.f);
  }
  if (isA) for (int i = tid; i < 128*68; i += NTHR) ((float*)memS)[i] = 0.f;
  gbarg(bar, bg);

  for (int t = 0; t < Lv; ++t){
    const int par_cur = t & 1, par_prev = (t+1) & 1;

    // ===== P1: gates (64 rows x 4 batches, weights read once) + LSTM -> h(t) =====
    {
      const float4* h4p = (const float4*)(hbuf  + par_prev*Bv*HIDv);
      const float4* r4p = (const float4*)(rcbuf + par_prev*Bv*NHv*HSv);
      float4* aS4 = (float4*)actS;                 // [bb][x 64 | rc 64 | h 128] f4
      if (tid < 256){
        int bbr = tid>>6, kr = tid&63;
        int ih = tid + 256; int bbh = ih>>7, kh = ih&127;
        float4 v0, v1;
        gld4_2(v0, v1, r4p + (b0+bbr)*64 + kr, h4p + (b0+bbh)*128 + kh);
        aS4[bbr*256 + 64 + kr]  = v0;
        aS4[bbh*256 + 128 + kh] = v1;
      } else {
        int ih = tid - 256; int bbh = ih>>7, kh = ih&127;
        float4 v = gld4(h4p + (b0+bbh)*128 + kh);
        aS4[bbh*256 + 128 + kh] = v;
        int ix = tid - 256; int bbx = ix>>6, kx = ix&63;
        aS4[bbx*256 + kx] = ((const float4*)x)[((size_t)(b0+bbx)*Lv + t)*64 + kx];
      }
      __syncthreads();

      const int kc = tid & 15, rgrp = tid >> 4;    // rgrp 0..31
      const int lr0 = rgrp*2;
      const int gr0 = (lr0>>4)*512 + rg*16 + (lr0&15);   // lr0 even -> gr1 = gr0+1
      const float4* wi0 = (const float4*)W_ih + (size_t)gr0*128;
      const float4* wh0 = (const float4*)W_hh + (size_t)gr0*128;
      const float4* aB  = (const float4*)actS;
      float acc[2][4] = {{0.f,0.f,0.f,0.f},{0.f,0.f,0.f,0.f}};
      #pragma unroll
      for (int i = 0; i < 8; ++i){
        int s = kc + 16*i;
        float4 w0 = wi0[s], w1 = wi0[128 + s];
        #pragma unroll
        for (int bb = 0; bb < 4; ++bb){
          float4 a = aB[bb*256 + s];
          acc[0][bb] += dot4(a, w0);
          acc[1][bb] += dot4(a, w1);
        }
      }
      #pragma unroll
      for (int i = 0; i < 8; ++i){
        int s = kc + 16*i;                          // h slot s+128 in actS
        float4 w0 = wh0[s], w1 = wh0[128 + s];
        #pragma unroll
        for (int bb = 0; bb < 4; ++bb){
          float4 a = aB[bb*256 + 128 + s];
          acc[0][bb] += dot4(a, w0);
          acc[1][bb] += dot4(a, w1);
        }
      }
      #pragma unroll
      for (int r = 0; r < 2; ++r)
        #pragma unroll
        for (int bb = 0; bb < 4; ++bb){
          float v = acc[r][bb];
          v += __shfl_xor(v,1); v += __shfl_xor(v,2);
          v += __shfl_xor(v,4); v += __shfl_xor(v,8);
          if (kc == 0) gS[lr0 + r][bb] = v;
        }
      __syncthreads();
      if (tid < 64){
        const int j = tid & 15, bb = tid >> 4;
        float ig = sigm (gS[     j][bb] + biasS[     j]);
        float fg = sigm (gS[16 + j][bb] + biasS[16 + j]);
        float gg = tanh_(gS[32 + j][bb] + biasS[32 + j]);
        float og = sigm (gS[48 + j][bb] + biasS[48 + j]);
        float cn = fmaf(fg, cS[j][bb], ig*gg);
        cS[j][bb] = cn;
        float hn = og * tanh_(cn);
        gst(hbuf + par_cur*Bv*HIDv + (size_t)(b0+bb)*HIDv + rg*16 + j, hn);
        if (t == Lv-1){
          hout [(size_t)(b0+bb)*HIDv + rg*16 + j] = hn;
          cout_[(size_t)(b0+bb)*HIDv + rg*16 + j] = cn;
        }
      }
    }
    gbarg(bar, bg);

    // ===== P2a: head GEMM split 32-way (rows li = rg+32k, + tail), all batches =====
    {
      const float4* hc4 = (const float4*)(hbuf + par_cur*Bv*HIDv);
      float4* aS4 = (float4*)actS;                 // reuse: [bb][128 f4] = h(t)
      aS4[tid] = gld4(hc4 + (b0 + (tid>>7))*128 + (tid & 127));
      __syncthreads();
      const int q = tid & 7, idx = tid >> 3;       // idx 0..63
      const int bb = idx & 3, rr = idx >> 2;       // rr 0..15
      const float4* h4 = aS4 + bb*128;
      #pragma unroll
      for (int pass = 0; pass < 2; ++pass){
        int li;
        if (pass == 0) li = rg + 32*rr;
        else { if (!(rg < 4 && rr == 0)) break; li = 512 + rg; }
        int n = li/129, d = li - n*129;
        const float4* w4 = (const float4*)W_head + (size_t)(n*195 + d)*128;
        float a0=0.f,a1=0.f,a2=0.f,a3=0.f;
        #pragma unroll
        for (int i = 0; i < 16; i += 4){
          a0 += dot4(h4[q+8*(i+0)], w4[q+8*(i+0)]);
          a1 += dot4(h4[q+8*(i+1)], w4[q+8*(i+1)]);
          a2 += dot4(h4[q+8*(i+2)], w4[q+8*(i+2)]);
          a3 += dot4(h4[q+8*(i+3)], w4[q+8*(i+3)]);
        }
        float acc = (a0+a1)+(a2+a3);
        acc += __shfl_xor(acc,1); acc += __shfl_xor(acc,2); acc += __shfl_xor(acc,4);
        if (q == 0){
          acc += b_head[n*195 + d];
          if (d == 128) acc = sigm(acc);           // write strength pre-sigmoided
          gst(hp + (size_t)(b0+bb)*520 + li, acc);
        }
      }
    }
    gbarg(bar, bg);

    // ===== P2b: attention (4 blocks/group) || out(t-1) (28 blocks/group) =====
    if (isA){
      const int b = abatch;
      for (int i = tid; i < 516; i += NTHR){
        int n = i/129, d = i - n*129;
        float v = gld(hp + (size_t)b*520 + i);
        if (d < 64)       rkS[n][d] = v;
        else if (d < 128) wkS[n][d-64] = v;
        else              strS[n] = v;
      }
      __syncthreads();
      { // QK^T for read & write keys, scale 1/8
        const int n = tid >> 7, m = tid & 127;
        const float4* m4  = (const float4*)&memS[m][0];
        const float4* rk4 = (const float4*)rkS[n];
        const float4* wk4 = (const float4*)wkS[n];
        float sr0=0.f,sr1=0.f,sw0=0.f,sw1=0.f;
        #pragma unroll
        for (int i = 0; i < 16; i += 2){
          float4 v0 = m4[i], v1 = m4[i+1];
          sr0 += dot4(v0, rk4[i]);   sw0 += dot4(v0, wk4[i]);
          sr1 += dot4(v1, rk4[i+1]); sw1 += dot4(v1, wk4[i+1]);
        }
        pr[n][m] = (sr0+sr1)*0.125f;
        pw[n][m] = (sw0+sw1)*0.125f;
      }
      __syncthreads();
      { // softmax rows: 8 waves, one (tensor,head) each
        const int w = tid >> 6, lane = tid & 63;
        float* rowp = (w < NHv) ? pr[w] : pw[w-NHv];
        float va = rowp[lane], vb = rowp[lane+64];
        float mx = fmaxf(va, vb);
        for (int off = 32; off > 0; off >>= 1) mx = fmaxf(mx, __shfl_xor(mx, off));
        float ea = __expf(va-mx), eb = __expf(vb-mx);
        float s = ea + eb;
        for (int off = 32; off > 0; off >>= 1) s += __shfl_xor(s, off);
        float inv = 1.f/s;
        rowp[lane] = ea*inv; rowp[lane+64] = eb*inv;
      }
      __syncthreads();
      if (tid < 256){ // rc = pr @ mem (pre-update)
        const int n = tid >> 6, hh = tid & 63;
        float a0=0.f,a1=0.f,a2=0.f,a3=0.f;
        for (int m = 0; m < 128; m += 4){
          a0 += pr[n][m+0]*memS[m+0][hh];
          a1 += pr[n][m+1]*memS[m+1][hh];
          a2 += pr[n][m+2]*memS[m+2][hh];
          a3 += pr[n][m+3]*memS[m+3][hh];
        }
        gst(rcbuf + par_cur*Bv*NHv*HSv + (size_t)(b*NHv + n)*HSv + hh, (a0+a1)+(a2+a3));
      }
      __syncthreads();
      { // mem += ww^T (str*wk)
        const int hh = tid & 63, mg = tid >> 6;
        const float s0 = strS[0]*wkS[0][hh], s1 = strS[1]*wkS[1][hh],
                    s2 = strS[2]*wkS[2][hh], s3 = strS[3]*wkS[3][hh];
        for (int m = mg; m < 128; m += 8){
          float add = pw[0][m]*s0 + pw[1][m]*s1 + pw[2][m]*s2 + pw[3][m]*s3;
          memS[m][hh] += add;
        }
      }
    } else if (t > 0){
      out_phase(t-1, b0, orank, tid,
                (const float4*)(hbuf  + par_prev*Bv*HIDv),
                (const float4*)(rcbuf + par_prev*Bv*NHv*HSv),
                W_out, b_out, out, outS);
    }
    gbarg(bar, bg);
  }

  // ===== final: out(255) || mem dump =====
  if (isA){
    for (int i = tid; i < MEMv*HSv; i += NTHR){
      int m = i >> 6, hh = i & 63;
      memv[((size_t)abatch*MEMv + m)*HSv + hh] = memS[m][hh];
    }
  } else {
    out_phase(Lv-1, b0, orank, tid,
              (const float4*)(hbuf  + Bv*HIDv),       // parity 1 = h(255)
              (const float4*)(rcbuf + Bv*NHv*HSv),    // parity 1 = rc(255)
              W_out, b_out, out, outS);
  }
}

extern "C" void kernel_launch(void* const* d_in, const int* in_sizes, int n_in,
                              void* d_out, int out_size, void* d_ws, size_t ws_size,
                              hipStream_t stream){
  const float* x      = (const float*)d_in[0];
  const float* W_ih   = (const float*)d_in[1];
  const float* W_hh   = (const float*)d_in[2];
  const float* b_ih   = (const float*)d_in[3];
  const float* b_hh   = (const float*)d_in[4];
  const float* W_head = (const float*)d_in[5];
  const float* b_head = (const float*)d_in[6];
  const float* W_out  = (const float*)d_in[7];
  const float* b_out  = (const float*)d_in[8];
  float* out = (float*)d_out;
  float* ws  = (float*)d_ws;

  (void)hipMemsetAsync(d_ws, 0, 4096, stream);   // barrier + ticket counters

  void* args[] = { (void*)&x, (void*)&W_ih, (void*)&W_hh, (void*)&b_ih, (void*)&b_hh,
                   (void*)&W_head, (void*)&b_head, (void*)&W_out, (void*)&b_out,
                   (void*)&out, (void*)&ws };
  (void)hipLaunchCooperativeKernel((const void*)ntm_kernel, dim3(NBLK), dim3(NTHR),
                                   args, 0, stream);
}